// Round 15
// baseline (163.481 us; speedup 1.0000x reference)
//
#include <hip/hip_runtime.h>
#include <math.h>

// Problem constants
#define NS 64    // sentences
#define NW 64    // words per sentence
#define NE 300   // embedding dim
#define NH 50    // hidden
#define NO 5     // output classes
#define SPIN_TICKS 150000ULL

// Session facts (measured):
//  - R13 calibration: f ~2.39 GHz, S(150k ticks) = 62.9us; k_scan_true ~23.8
//    (dominant), k_reps_true ~14.1, gaps ~0. k_scan VGPR_Count=64 -> weights
//    not register-resident (reload/spill per step).
//  - R14 pin (asm "+v") produced ZERO delta -> allocator likely spilled the
//    pinned values to scratch (same cost as reloads). R15 adds
//    amdgpu_waves_per_eu(1,1) to kill the occupancy heuristic, swaps
//    ds_swizzle (~120cy LDS latency on the serial chain) for DPP quad_perm
//    (~5cy VALU), and re-spins k_scan + calibrator for exact attribution.
//  - R8 f16 weights 78->48; R10 depth-4 X prefetch 48->42.7; R12 Phase-D
//    octet split 42.7->37.9. Best clean build: R12 37.9us.

typedef __fp16 half2v __attribute__((ext_vector_type(2)));

__device__ __forceinline__ float fdot2(half2v a, half2v b, float c) {
  return __builtin_amdgcn_fdot2(a, b, c, false);   // v_dot2_f32_f16
}
__device__ __forceinline__ float fast_tanh(float x) {
  x = fminf(15.f, fmaxf(-15.f, x));
  const float e = __expf(2.f * x);
  return 1.f - 2.f * __builtin_amdgcn_rcpf(e + 1.f);
}
__device__ __forceinline__ float fast_sigmoid(float x) {
  return __builtin_amdgcn_rcpf(1.f + __expf(-x));
}
__device__ __forceinline__ void tail_spin() {
  const unsigned long long t0 = clock64();
  while (clock64() - t0 < SPIN_TICKS) {}
}

// d_ws layout:
//   [64 .. 64+19200) floats    Xg  (2*64*3*50)
//   then 9600 u32              pw  (packed f16x2 weights, [dg][j][32-pad])

// ---------------------------------------------------------------------------
// K1: per-sentence reps + x-part preactivations; block 64 packs the weights.
// Identical to R14.
// ---------------------------------------------------------------------------
__global__ __launch_bounds__(512) void k_reps(
    const int* __restrict__ doc, const float* __restrict__ emb,
    const float* __restrict__ Wword, const float* __restrict__ bword,
    const float* __restrict__ w1, const float* __restrict__ b1,
    const float* __restrict__ w2, const float* __restrict__ b2,
    const float* __restrict__ w3, const float* __restrict__ b3,
    const float* __restrict__ Wfi, const float* __restrict__ bfi,
    const float* __restrict__ Wff, const float* __restrict__ bff,
    const float* __restrict__ Wfg, const float* __restrict__ bfg,
    const float* __restrict__ Wbi, const float* __restrict__ bbi,
    const float* __restrict__ Wbf, const float* __restrict__ bbf,
    const float* __restrict__ Wbg, const float* __restrict__ bbg,
    float* __restrict__ Xg, unsigned int* __restrict__ pw)
{
  __shared__ int   idxs[NW];
  __shared__ float sv[5][304];    // 0: word-sum; 1..4: rows 0,1,62,63
  __shared__ float ph1[304];      // group-1 partial of the w-sum
  __shared__ float dots[5][NH];
  __shared__ float reps_s[NH];

  const int s = blockIdx.x, tid = threadIdx.x;

  if (s == NS) {
    // weight-packing block: pw[(dg*50 + j)*32 + c] = f16x2 (w[2c], w[2c+1])
#pragma unroll 8
    for (int idx = tid; idx < 6 * 50 * 25; idx += 512) {
      const int c  = idx % 25;
      const int j  = (idx / 25) % 50;
      const int dg = idx / (25 * 50);     // (d*3+gate), 0..5
      const float* Wp;
      switch (dg) {
        case 0: Wp = Wfi; break;
        case 1: Wp = Wff; break;
        case 2: Wp = Wfg; break;
        case 3: Wp = Wbi; break;
        case 4: Wp = Wbf; break;
        default: Wp = Wbg; break;
      }
      const int base = j * 100 + 50 + 2 * c;
      const half2v v = __builtin_amdgcn_cvt_pkrtz(Wp[base], Wp[base + 1]);
      pw[(dg * 50 + j) * 32 + c] = __builtin_bit_cast(unsigned int, v);
    }
    return;
  }

  if (tid < NW) idxs[tid] = doc[s * NW + tid];
  __syncthreads();

  // Phase B: column sums of the 64 gathered rows, 2 groups x 32-deep.
  const int p = tid >> 8, et = tid & 255;
  for (int e = et; e < NE; e += 256) {
    float acc = 0.f;
    const int w0 = p * 32;
#pragma unroll 16
    for (int w = w0; w < w0 + 32; ++w)
      acc += emb[(size_t)idxs[w] * NE + e];
    if (p == 0) sv[0][e] = acc; else ph1[e] = acc;
    if (p == 0) {
      sv[1][e] = emb[(size_t)idxs[0]  * NE + e];
      sv[2][e] = emb[(size_t)idxs[1]  * NE + e];
    } else {
      sv[3][e] = emb[(size_t)idxs[62] * NE + e];
      sv[4][e] = emb[(size_t)idxs[63] * NE + e];
    }
  }
  __syncthreads();
  if (tid < NE) sv[0][tid] += ph1[tid];
  __syncthreads();

  // Phase C: 5 families x 50 outputs, 300-dots against W_word rows.
  if (tid < 5 * NH) {
    const int fam = tid / NH, i = tid % NH;
    const float4* v4 = (const float4*)&sv[fam][0];
    const float4* w4 = (const float4*)(Wword + (size_t)i * NE);
    float a0 = 0.f, a1 = 0.f;
#pragma unroll
    for (int c = 0; c < NE / 4; ++c) {
      const float4 v = v4[c], w = w4[c];
      a0 += v.x * w.x + v.y * w.y;
      a1 += v.z * w.z + v.w * w.w;
    }
    dots[fam][i] = a0 + a1;
  }
  __syncthreads();

  // Phase D: conv means + tanh + average -> reps_s (octet split + reduce).
  if (tid < 8 * NH) {
    const int o = tid >> 3, part = tid & 7;
    float m1 = 0.f, m2 = 0.f, m3 = 0.f;
    for (int i = part; i < NH; i += 8) {
      const float bw    = bword[i];
      const float total = dots[0][i] + 64.f * bw;
      const float e0  = dots[1][i] + bw;
      const float e1  = dots[2][i] + bw;
      const float e62 = dots[3][i] + bw;
      const float e63 = dots[4][i] + bw;
      m1 += w1[o * NH + i] * total;
      m2 += w2[(o * NH + i) * 2 + 0] * (total - e63)
          + w2[(o * NH + i) * 2 + 1] * (total - e0);
      m3 += w3[(o * NH + i) * 3 + 0] * (total - e62 - e63)
          + w3[(o * NH + i) * 3 + 1] * (total - e0 - e63)
          + w3[(o * NH + i) * 3 + 2] * (total - e0 - e1);
    }
#pragma unroll
    for (int m = 1; m < 8; m <<= 1) {
      m1 += __shfl_xor(m1, m);
      m2 += __shfl_xor(m2, m);
      m3 += __shfl_xor(m3, m);
    }
    if (part == 0) {
      m1 = b1[o] + m1 * (1.f / 64.f);
      m2 = b2[o] + m2 * (1.f / 63.f);
      m3 = b3[o] + m3 * (1.f / 62.f);
      reps_s[o] = (fast_tanh(m1) + fast_tanh(m2) + fast_tanh(m3)) * (1.f / 3.f);
    }
  }
  __syncthreads();

  // Phase E: x-part gate preactivations for both directions.
  if (tid < 6 * NH) {
    const int dg = tid / NH, j = tid % NH;
    const float* Wp; const float* bp;
    switch (dg) {
      case 0: Wp = Wfi; bp = bfi; break;
      case 1: Wp = Wff; bp = bff; break;
      case 2: Wp = Wfg; bp = bfg; break;
      case 3: Wp = Wbi; bp = bbi; break;
      case 4: Wp = Wbf; bp = bbf; break;
      default: Wp = Wbg; bp = bbg; break;
    }
    float acc = bp[j];
    for (int k = 0; k < NH; ++k) acc += Wp[j * 100 + k] * reps_s[k];
    const int dir = dg / 3, gate = dg % 3;
    Xg[((dir * NS + s) * 3 + gate) * NH + j] = acc;
  }
}

// ---------------------------------------------------------------------------
// K2: 1 block x 2 waves. Changes vs R14:
//  (1) amdgpu_waves_per_eu(1,1): allocator occupancy target = 1 wave/EU ->
//      free to hold ~110 VGPRs live, no spill of the pinned weights.
//  (2) DPP quad_perm[1,0,3,2] replaces ds_swizzle for the xor-1 partner h
//      (VALU ~5cy vs LDS ~120cy on the serial chain).
//  (3) tail_spin appended (diagnostic; exposes VGPR + true duration).
// ---------------------------------------------------------------------------
struct X3 { float i, f, g; };

__global__ __launch_bounds__(128, 1)
__attribute__((amdgpu_waves_per_eu(1, 1)))
void k_scan(
    const float* __restrict__ Xg, const unsigned int* __restrict__ pw,
    const float* __restrict__ Wout, const float* __restrict__ bout,
    float* __restrict__ out)
{
  __shared__ float gsum_sh[2 * NH];

  const int tid = threadIdx.x;
  const int d   = tid >> 6;                 // wave = direction
  const int lane = tid & 63;
  const int j   = (lane < NH) ? lane : 0;   // lanes 50..63 shadow lane 0

  // Prologue: vectorizable loads from [dg][j][32-pad]; pin into VGPRs.
  const unsigned int* wpI = pw + ((d * 3 + 0) * 50 + j) * 32;
  const unsigned int* wpF = pw + ((d * 3 + 1) * 50 + j) * 32;
  const unsigned int* wpG = pw + ((d * 3 + 2) * 50 + j) * 32;

  unsigned int wiu[25], wfu[25], wgu[25];
#pragma unroll
  for (int c = 0; c < 25; ++c) {
    wiu[c] = wpI[c];
    wfu[c] = wpF[c];
    wgu[c] = wpG[c];
  }
#pragma unroll
  for (int c = 0; c < 25; ++c) {
    asm volatile("" : "+v"(wiu[c]), "+v"(wfu[c]), "+v"(wgu[c]));
  }

  const float* Xd = Xg + d * NS * 3 * NH;

  auto ldx = [&](int t) -> X3 {
    const int tt = d ? (NS - 1 - t) : t;
    X3 r;
    r.i = Xd[tt * 150 + j];
    r.f = Xd[tt * 150 + 50 + j];
    r.g = Xd[tt * 150 + 100 + j];
    return r;
  };

  float hj = 0.f, hs = 0.f;

  auto dostep = [&](X3 x) {
    float ai0 = x.i, af0 = x.f, ag0 = x.g;
    float ai1 = 0.f, af1 = 0.f, ag1 = 0.f;
    // partner h via DPP quad_perm [1,0,3,2] (xor-1), pure VALU
    const int hpi = __builtin_amdgcn_update_dpp(
        0, __builtin_bit_cast(int, hj), 0xB1 /*[1,0,3,2]*/, 0xF, 0xF, true);
    const float hpart = __builtin_bit_cast(float, hpi);
    const half2v hpk = __builtin_amdgcn_cvt_pkrtz(hj, hpart);
    const int packed = __builtin_bit_cast(int, hpk);
#pragma unroll
    for (int c = 0; c < 25; ++c) {
      const half2v hk2 = __builtin_bit_cast(half2v,
          __builtin_amdgcn_readlane(packed, 2 * c));
      const half2v wi = __builtin_bit_cast(half2v, wiu[c]);
      const half2v wf = __builtin_bit_cast(half2v, wfu[c]);
      const half2v wg = __builtin_bit_cast(half2v, wgu[c]);
      if (c & 1) {
        ai1 = fdot2(wi, hk2, ai1);
        af1 = fdot2(wf, hk2, af1);
        ag1 = fdot2(wg, hk2, ag1);
      } else {
        ai0 = fdot2(wi, hk2, ai0);
        af0 = fdot2(wf, hk2, af0);
        ag0 = fdot2(wg, hk2, ag0);
      }
    }
    const float it = fast_sigmoid(ai0 + ai1);
    const float ft = fast_sigmoid(af0 + af1);
    const float gt = fast_tanh(ag0 + ag1);
    hj = fast_tanh(it * gt + ft * hj);
    hs += hj;
  };

  // Depth-4 rolling prefetch: named slots, statically indexed.
  X3 p0 = ldx(0), p1 = ldx(1), p2 = ldx(2), p3 = ldx(3);

#pragma unroll 1
  for (int k = 0; k < NS / 4; ++k) {
    const int n = 4 * k;
    const int q0 = (n + 4 < NS) ? n + 4 : NS - 1;
    const int q1 = (n + 5 < NS) ? n + 5 : NS - 1;
    const int q2 = (n + 6 < NS) ? n + 6 : NS - 1;
    const int q3 = (n + 7 < NS) ? n + 7 : NS - 1;
    X3 c0 = p0; p0 = ldx(q0); dostep(c0);
    X3 c1 = p1; p1 = ldx(q1); dostep(c1);
    X3 c2 = p2; p2 = ldx(q2); dostep(c2);
    X3 c3 = p3; p3 = ldx(q3); dostep(c3);
  }

  if (lane < NH) gsum_sh[d * NH + lane] = hs * (1.f / 64.f);
  __syncthreads();

  // Epilogue (wave 0): logits + softmax
  if (d == 0) {
    float lg = 0.f;
    if (lane < NO) {
      float acc = bout[lane];
      for (int k = 0; k < 2 * NH; ++k) acc += Wout[lane * 2 * NH + k] * gsum_sh[k];
      lg = acc;
    }
    const float l0 = __shfl(lg, 0), l1 = __shfl(lg, 1), l2 = __shfl(lg, 2),
                l3 = __shfl(lg, 3), l4 = __shfl(lg, 4);
    if (lane == 0) {
      const float m = fmaxf(fmaxf(fmaxf(l0, l1), fmaxf(l2, l3)), l4);
      const float e0 = __expf(l0 - m), e1 = __expf(l1 - m), e2 = __expf(l2 - m),
                  e3 = __expf(l3 - m), e4 = __expf(l4 - m);
      const float se = e0 + e1 + e2 + e3 + e4;
      out[0] = e0 / se; out[1] = e1 / se; out[2] = e2 / se;
      out[3] = e3 / se; out[4] = e4 / se;
    }
  }
  tail_spin();
}

// ------------------------- standalone spin calibrator ----------------------
__global__ __launch_bounds__(64) void k_spin_cal() {
  tail_spin();
}

extern "C" void kernel_launch(void* const* d_in, const int* in_sizes, int n_in,
                              void* d_out, int out_size, void* d_ws, size_t ws_size,
                              hipStream_t stream) {
  const int*   doc   = (const int*)  d_in[0];
  const float* emb   = (const float*)d_in[1];
  const float* Wword = (const float*)d_in[2];
  const float* bword = (const float*)d_in[3];
  const float* w1    = (const float*)d_in[4];
  const float* b1    = (const float*)d_in[5];
  const float* w2    = (const float*)d_in[6];
  const float* b2    = (const float*)d_in[7];
  const float* w3    = (const float*)d_in[8];
  const float* b3    = (const float*)d_in[9];
  const float* Wfi   = (const float*)d_in[10];
  const float* bfi   = (const float*)d_in[11];
  const float* Wff   = (const float*)d_in[12];
  const float* bff   = (const float*)d_in[13];
  const float* Wfg   = (const float*)d_in[14];
  const float* bfg   = (const float*)d_in[15];
  const float* Wbi   = (const float*)d_in[16];
  const float* bbi   = (const float*)d_in[17];
  const float* Wbf   = (const float*)d_in[18];
  const float* bbf   = (const float*)d_in[19];
  const float* Wbg   = (const float*)d_in[20];
  const float* bbg   = (const float*)d_in[21];
  const float* Wout  = (const float*)d_in[22];
  const float* bout  = (const float*)d_in[23];

  float* Xg = (float*)d_ws + 64;                                  // 19200 floats
  unsigned int* pw = (unsigned int*)((float*)d_ws + 64 + 19200);  // 9600 u32

  k_reps<<<dim3(NS + 1), dim3(512), 0, stream>>>(
      doc, emb, Wword, bword, w1, b1, w2, b2, w3, b3,
      Wfi, bfi, Wff, bff, Wfg, bfg, Wbi, bbi, Wbf, bbf, Wbg, bbg,
      Xg, pw);

  k_scan<<<dim3(1), dim3(128), 0, stream>>>(
      Xg, pw, Wout, bout, (float*)d_out);

  k_spin_cal<<<dim3(1), dim3(64), 0, stream>>>();
}

// Round 16
// 45.758 us; speedup vs baseline: 3.5727x; 3.5727x over previous
//
#include <hip/hip_runtime.h>
#include <math.h>

// Problem constants
#define NS 64    // sentences
#define NW 64    // words per sentence
#define NE 300   // embedding dim
#define NH 50    // hidden
#define NO 5     // output classes

// Session facts (measured):
//  - R13/R15 calibration (S=62.9us @ ~2.39GHz): k_reps_true ~14.1us,
//    k_scan_true ~23.8us, gaps ~0. Best clean build: R12 @ 37.9us.
//  - k_scan VGPR_Count pinned at 64 across R13/R14/R15 despite asm "+v" pins
//    AND amdgpu_waves_per_eu(1,1): the allocator refuses to hold 75 weight
//    dwords/lane -> ~900cy/step scratch/remat reloads dominate the scan.
//    R14 (pin) and R15 (waves_per_eu + DPP-for-swizzle) were BOTH zero-delta.
//  - R16: stop fighting the allocator. 6 waves (wave = dir x gate): 25 weight
//    dwords/lane (fits easily), one barrier/step gate exchange (R4-proven
//    parity double-buffer), wave-private h in registers, depth-4 X prefetch.
//  - R8 f16 weights 78->48; R10 depth-4 X prefetch 48->42.7; R12 Phase-D
//    octet split 42.7->37.9. R9-style bulk staging/flags REGRESSED; avoid.

typedef __fp16 half2v __attribute__((ext_vector_type(2)));

__device__ __forceinline__ float fdot2(half2v a, half2v b, float c) {
  return __builtin_amdgcn_fdot2(a, b, c, false);   // v_dot2_f32_f16
}
__device__ __forceinline__ float fast_tanh(float x) {
  x = fminf(15.f, fmaxf(-15.f, x));
  const float e = __expf(2.f * x);
  return 1.f - 2.f * __builtin_amdgcn_rcpf(e + 1.f);
}
__device__ __forceinline__ float fast_sigmoid(float x) {
  return __builtin_amdgcn_rcpf(1.f + __expf(-x));
}

// d_ws layout:
//   [64 .. 64+19200) floats    Xg  (2*64*3*50)
//   then 9600 u32              pw  (packed f16x2 weights, [dg][c][64-pad j])

// ---------------------------------------------------------------------------
// K1: per-sentence reps + x-part preactivations; block 64 packs the weights.
// Unchanged from R12/R14 except the pw layout is [dg][c][64-pad j]
// (lane-coalesced for the 6-wave scan prologue).
// ---------------------------------------------------------------------------
__global__ __launch_bounds__(512) void k_reps(
    const int* __restrict__ doc, const float* __restrict__ emb,
    const float* __restrict__ Wword, const float* __restrict__ bword,
    const float* __restrict__ w1, const float* __restrict__ b1,
    const float* __restrict__ w2, const float* __restrict__ b2,
    const float* __restrict__ w3, const float* __restrict__ b3,
    const float* __restrict__ Wfi, const float* __restrict__ bfi,
    const float* __restrict__ Wff, const float* __restrict__ bff,
    const float* __restrict__ Wfg, const float* __restrict__ bfg,
    const float* __restrict__ Wbi, const float* __restrict__ bbi,
    const float* __restrict__ Wbf, const float* __restrict__ bbf,
    const float* __restrict__ Wbg, const float* __restrict__ bbg,
    float* __restrict__ Xg, unsigned int* __restrict__ pw)
{
  __shared__ int   idxs[NW];
  __shared__ float sv[5][304];    // 0: word-sum; 1..4: rows 0,1,62,63
  __shared__ float ph1[304];      // group-1 partial of the w-sum
  __shared__ float dots[5][NH];
  __shared__ float reps_s[NH];

  const int s = blockIdx.x, tid = threadIdx.x;

  if (s == NS) {
    // weight-packing block: pw[(dg*25 + c)*64 + j] = f16x2 (w[2c], w[2c+1])
#pragma unroll 8
    for (int idx = tid; idx < 6 * 25 * 50; idx += 512) {
      const int j  = idx % 50;
      const int c  = (idx / 50) % 25;
      const int dg = idx / (25 * 50);     // (d*3+gate), 0..5
      const float* Wp;
      switch (dg) {
        case 0: Wp = Wfi; break;
        case 1: Wp = Wff; break;
        case 2: Wp = Wfg; break;
        case 3: Wp = Wbi; break;
        case 4: Wp = Wbf; break;
        default: Wp = Wbg; break;
      }
      const int base = j * 100 + 50 + 2 * c;
      const half2v v = __builtin_amdgcn_cvt_pkrtz(Wp[base], Wp[base + 1]);
      pw[(dg * 25 + c) * 64 + j] = __builtin_bit_cast(unsigned int, v);
    }
    return;
  }

  if (tid < NW) idxs[tid] = doc[s * NW + tid];
  __syncthreads();

  // Phase B: column sums of the 64 gathered rows, 2 groups x 32-deep.
  const int p = tid >> 8, et = tid & 255;
  for (int e = et; e < NE; e += 256) {
    float acc = 0.f;
    const int w0 = p * 32;
#pragma unroll 16
    for (int w = w0; w < w0 + 32; ++w)
      acc += emb[(size_t)idxs[w] * NE + e];
    if (p == 0) sv[0][e] = acc; else ph1[e] = acc;
    if (p == 0) {
      sv[1][e] = emb[(size_t)idxs[0]  * NE + e];
      sv[2][e] = emb[(size_t)idxs[1]  * NE + e];
    } else {
      sv[3][e] = emb[(size_t)idxs[62] * NE + e];
      sv[4][e] = emb[(size_t)idxs[63] * NE + e];
    }
  }
  __syncthreads();
  if (tid < NE) sv[0][tid] += ph1[tid];
  __syncthreads();

  // Phase C: 5 families x 50 outputs, 300-dots against W_word rows.
  if (tid < 5 * NH) {
    const int fam = tid / NH, i = tid % NH;
    const float4* v4 = (const float4*)&sv[fam][0];
    const float4* w4 = (const float4*)(Wword + (size_t)i * NE);
    float a0 = 0.f, a1 = 0.f;
#pragma unroll
    for (int c = 0; c < NE / 4; ++c) {
      const float4 v = v4[c], w = w4[c];
      a0 += v.x * w.x + v.y * w.y;
      a1 += v.z * w.z + v.w * w.w;
    }
    dots[fam][i] = a0 + a1;
  }
  __syncthreads();

  // Phase D: conv means + tanh + average -> reps_s (octet split + reduce).
  if (tid < 8 * NH) {
    const int o = tid >> 3, part = tid & 7;
    float m1 = 0.f, m2 = 0.f, m3 = 0.f;
    for (int i = part; i < NH; i += 8) {
      const float bw    = bword[i];
      const float total = dots[0][i] + 64.f * bw;
      const float e0  = dots[1][i] + bw;
      const float e1  = dots[2][i] + bw;
      const float e62 = dots[3][i] + bw;
      const float e63 = dots[4][i] + bw;
      m1 += w1[o * NH + i] * total;
      m2 += w2[(o * NH + i) * 2 + 0] * (total - e63)
          + w2[(o * NH + i) * 2 + 1] * (total - e0);
      m3 += w3[(o * NH + i) * 3 + 0] * (total - e62 - e63)
          + w3[(o * NH + i) * 3 + 1] * (total - e0 - e63)
          + w3[(o * NH + i) * 3 + 2] * (total - e0 - e1);
    }
#pragma unroll
    for (int m = 1; m < 8; m <<= 1) {
      m1 += __shfl_xor(m1, m);
      m2 += __shfl_xor(m2, m);
      m3 += __shfl_xor(m3, m);
    }
    if (part == 0) {
      m1 = b1[o] + m1 * (1.f / 64.f);
      m2 = b2[o] + m2 * (1.f / 63.f);
      m3 = b3[o] + m3 * (1.f / 62.f);
      reps_s[o] = (fast_tanh(m1) + fast_tanh(m2) + fast_tanh(m3)) * (1.f / 3.f);
    }
  }
  __syncthreads();

  // Phase E: x-part gate preactivations for both directions.
  if (tid < 6 * NH) {
    const int dg = tid / NH, j = tid % NH;
    const float* Wp; const float* bp;
    switch (dg) {
      case 0: Wp = Wfi; bp = bfi; break;
      case 1: Wp = Wff; bp = bff; break;
      case 2: Wp = Wfg; bp = bfg; break;
      case 3: Wp = Wbi; bp = bbi; break;
      case 4: Wp = Wbf; bp = bbf; break;
      default: Wp = Wbg; bp = bbg; break;
    }
    float acc = bp[j];
    for (int k = 0; k < NH; ++k) acc += Wp[j * 100 + k] * reps_s[k];
    const int dir = dg / 3, gate = dg % 3;
    Xg[((dir * NS + s) * 3 + gate) * NH + j] = acc;
  }
}

// ---------------------------------------------------------------------------
// K2: 1 block x 384 threads, wave = (direction, gate). Each lane holds ONE
// gate row: 25 f16x2 dwords (register-resident under the observed 64-VGPR
// ceiling). Per step: dot2 chain -> activation -> gate_sh[parity] write ->
// ONE barrier -> read 3 gates -> redundant in-register h update (no h via
// LDS; DPP xor-1 pairs + cvt_pk + readlane broadcast). Depth-4 X prefetch.
// ---------------------------------------------------------------------------
__global__ __launch_bounds__(384, 1) void k_scan(
    const float* __restrict__ Xg, const unsigned int* __restrict__ pw,
    const float* __restrict__ Wout, const float* __restrict__ bout,
    float* __restrict__ out)
{
  __shared__ float gate_sh[2][2][3][64];   // [parity][dir][gate][lane]
  __shared__ float gsum_sh[2 * NH];

  const int tid  = threadIdx.x;
  const int wid  = tid >> 6, lane = tid & 63;
  const int d    = wid / 3, g = wid % 3;    // direction, gate
  const int j    = (lane < NH) ? lane : 0;  // lanes 50..63 shadow lane 0
  const int dg   = d * 3 + g;

  // Prologue: 25 lane-coalesced dword loads (this wave's gate row, f16x2).
  unsigned int wu[25];
#pragma unroll
  for (int c = 0; c < 25; ++c) wu[c] = pw[(dg * 25 + c) * 64 + j];

  // X for this (d, g): Xg[(d*64 + t)*150 + g*50 + j]
  const float* Xd = Xg + d * NS * 3 * NH + g * NH + j;
  auto ldx = [&](int t) -> float {
    const int tt = d ? (NS - 1 - t) : t;
    return Xd[tt * 150];
  };

  float hj = 0.f, hs = 0.f;
  float p0 = ldx(0), p1 = ldx(1), p2 = ldx(2), p3 = ldx(3);

#pragma unroll 1
  for (int n = 0; n < NS; ++n) {
    // rotate the depth-4 prefetch window
    const float x = p0;
    p0 = p1; p1 = p2; p2 = p3;
    const int q = (n + 4 < NS) ? n + 4 : NS - 1;
    p3 = ldx(q);

    // pack (h[2c], h[2c+1]) pairs: partner via DPP quad_perm[1,0,3,2] (xor-1)
    const int hpi = __builtin_amdgcn_update_dpp(
        0, __builtin_bit_cast(int, hj), 0xB1, 0xF, 0xF, true);
    const half2v hpk = __builtin_amdgcn_cvt_pkrtz(
        hj, __builtin_bit_cast(float, hpi));
    const int packed = __builtin_bit_cast(int, hpk);

    float a0 = x, a1 = 0.f;   // even/odd split chains (depth 13)
#pragma unroll
    for (int c = 0; c < 25; ++c) {
      const half2v hk2 = __builtin_bit_cast(half2v,
          __builtin_amdgcn_readlane(packed, 2 * c));
      const half2v wv = __builtin_bit_cast(half2v, wu[c]);
      if (c & 1) a1 = fdot2(wv, hk2, a1);
      else       a0 = fdot2(wv, hk2, a0);
    }
    const float a = a0 + a1;

    const float act = (g == 2) ? fast_tanh(a) : fast_sigmoid(a);
    const int par = n & 1;
    if (lane < NH) gate_sh[par][d][g][lane] = act;

    __syncthreads();   // single rendezvous per step (parity buffer -> no WAR)

    const float iv = gate_sh[par][d][0][j];
    const float fv = gate_sh[par][d][1][j];
    const float gv = gate_sh[par][d][2][j];
    hj = fast_tanh(iv * gv + fv * hj);   // redundant across the 3 gate-waves
    hs += hj;
  }

  if (g == 0 && lane < NH) gsum_sh[d * NH + lane] = hs * (1.f / 64.f);
  __syncthreads();

  // Epilogue (wave 0): logits + softmax
  if (wid == 0) {
    float lg = 0.f;
    if (lane < NO) {
      float acc = bout[lane];
      for (int k = 0; k < 2 * NH; ++k) acc += Wout[lane * 2 * NH + k] * gsum_sh[k];
      lg = acc;
    }
    const float l0 = __shfl(lg, 0), l1 = __shfl(lg, 1), l2 = __shfl(lg, 2),
                l3 = __shfl(lg, 3), l4 = __shfl(lg, 4);
    if (lane == 0) {
      const float m = fmaxf(fmaxf(fmaxf(l0, l1), fmaxf(l2, l3)), l4);
      const float e0 = __expf(l0 - m), e1 = __expf(l1 - m), e2 = __expf(l2 - m),
                  e3 = __expf(l3 - m), e4 = __expf(l4 - m);
      const float se = e0 + e1 + e2 + e3 + e4;
      out[0] = e0 / se; out[1] = e1 / se; out[2] = e2 / se;
      out[3] = e3 / se; out[4] = e4 / se;
    }
  }
}

extern "C" void kernel_launch(void* const* d_in, const int* in_sizes, int n_in,
                              void* d_out, int out_size, void* d_ws, size_t ws_size,
                              hipStream_t stream) {
  const int*   doc   = (const int*)  d_in[0];
  const float* emb   = (const float*)d_in[1];
  const float* Wword = (const float*)d_in[2];
  const float* bword = (const float*)d_in[3];
  const float* w1    = (const float*)d_in[4];
  const float* b1    = (const float*)d_in[5];
  const float* w2    = (const float*)d_in[6];
  const float* b2    = (const float*)d_in[7];
  const float* w3    = (const float*)d_in[8];
  const float* b3    = (const float*)d_in[9];
  const float* Wfi   = (const float*)d_in[10];
  const float* bfi   = (const float*)d_in[11];
  const float* Wff   = (const float*)d_in[12];
  const float* bff   = (const float*)d_in[13];
  const float* Wfg   = (const float*)d_in[14];
  const float* bfg   = (const float*)d_in[15];
  const float* Wbi   = (const float*)d_in[16];
  const float* bbi   = (const float*)d_in[17];
  const float* Wbf   = (const float*)d_in[18];
  const float* bbf   = (const float*)d_in[19];
  const float* Wbg   = (const float*)d_in[20];
  const float* bbg   = (const float*)d_in[21];
  const float* Wout  = (const float*)d_in[22];
  const float* bout  = (const float*)d_in[23];

  float* Xg = (float*)d_ws + 64;                                  // 19200 floats
  unsigned int* pw = (unsigned int*)((float*)d_ws + 64 + 19200);  // 9600 u32

  k_reps<<<dim3(NS + 1), dim3(512), 0, stream>>>(
      doc, emb, Wword, bword, w1, b1, w2, b2, w3, b3,
      Wfi, bfi, Wff, bff, Wfg, bfg, Wbi, bbi, Wbf, bbf, Wbg, bbg,
      Xg, pw);

  k_scan<<<dim3(1), dim3(384), 0, stream>>>(
      Xg, pw, Wout, bout, (float*)d_out);
}

// Round 17
// 37.641 us; speedup vs baseline: 4.3431x; 1.2156x over previous
//
#include <hip/hip_runtime.h>
#include <math.h>

// Problem constants
#define NS 64    // sentences
#define NW 64    // words per sentence
#define NE 300   // embedding dim
#define NH 50    // hidden
#define NO 5     // output classes

// Session facts (measured):
//  - Calibrated (R13/R15, S=62.9us @ ~2.39GHz): k_reps_true ~14.1us,
//    k_scan_true ~23.8us, gaps ~0. Best clean build: R12 @ 37.9us.
//  - k_scan loop is INSTRUCTION-ISSUE bound: ~190 instr x 2cy = ~370cy/step.
//    ~75 of those are scalar remat weight loads (R12 layout put a lane's
//    weights 200B apart -> unmergeable). R14's contiguous layout + asm pins
//    forced 75 live VGPRs -> scratch spill -> zero delta (pins were the
//    poison). R16 6-wave barrier scan = ~31us (barriers cost more). R17:
//    contiguous [dg][j][28-pad] layout, NO pins -> remat merges to dwordx4.
//  - R8 f16 weights 78->48; R10 depth-4 X prefetch 48->42.7; R12 Phase-D
//    octet split 42.7->37.9. Barrier-per-step scans and bulk-LDS staging
//    REGRESSED; avoid.

typedef __fp16 half2v __attribute__((ext_vector_type(2)));

__device__ __forceinline__ float fdot2(half2v a, half2v b, float c) {
  return __builtin_amdgcn_fdot2(a, b, c, false);   // v_dot2_f32_f16
}
__device__ __forceinline__ float fast_tanh(float x) {
  x = fminf(15.f, fmaxf(-15.f, x));
  const float e = __expf(2.f * x);
  return 1.f - 2.f * __builtin_amdgcn_rcpf(e + 1.f);
}
__device__ __forceinline__ float fast_sigmoid(float x) {
  return __builtin_amdgcn_rcpf(1.f + __expf(-x));
}

// d_ws layout:
//   [64 .. 64+19200) floats    Xg  (2*64*3*50)
//   then 8400 u32              pw  (packed f16x2 weights, [dg][j][28-pad c])

// ---------------------------------------------------------------------------
// K1: per-sentence reps + x-part preactivations; block 64 packs the weights.
// Identical to R12 except the pw layout: [dg][j][28-pad c] (25 contiguous
// dwords per lane, 112B stride = 16B aligned -> dwordx4-mergeable).
// ---------------------------------------------------------------------------
__global__ __launch_bounds__(512) void k_reps(
    const int* __restrict__ doc, const float* __restrict__ emb,
    const float* __restrict__ Wword, const float* __restrict__ bword,
    const float* __restrict__ w1, const float* __restrict__ b1,
    const float* __restrict__ w2, const float* __restrict__ b2,
    const float* __restrict__ w3, const float* __restrict__ b3,
    const float* __restrict__ Wfi, const float* __restrict__ bfi,
    const float* __restrict__ Wff, const float* __restrict__ bff,
    const float* __restrict__ Wfg, const float* __restrict__ bfg,
    const float* __restrict__ Wbi, const float* __restrict__ bbi,
    const float* __restrict__ Wbf, const float* __restrict__ bbf,
    const float* __restrict__ Wbg, const float* __restrict__ bbg,
    float* __restrict__ Xg, unsigned int* __restrict__ pw)
{
  __shared__ int   idxs[NW];
  __shared__ float sv[5][304];    // 0: word-sum; 1..4: rows 0,1,62,63
  __shared__ float ph1[304];      // group-1 partial of the w-sum
  __shared__ float dots[5][NH];
  __shared__ float reps_s[NH];

  const int s = blockIdx.x, tid = threadIdx.x;

  if (s == NS) {
    // weight-packing block: pw[(dg*50 + j)*28 + c] = f16x2 (w[2c], w[2c+1])
    // c=25..27 zero-padded (keeps x4 tails harmless if ever read).
#pragma unroll 8
    for (int idx = tid; idx < 6 * 50 * 28; idx += 512) {
      const int c  = idx % 28;
      const int j  = (idx / 28) % 50;
      const int dg = idx / (28 * 50);     // (d*3+gate), 0..5
      unsigned int val = 0u;
      if (c < 25) {
        const float* Wp;
        switch (dg) {
          case 0: Wp = Wfi; break;
          case 1: Wp = Wff; break;
          case 2: Wp = Wfg; break;
          case 3: Wp = Wbi; break;
          case 4: Wp = Wbf; break;
          default: Wp = Wbg; break;
        }
        const int base = j * 100 + 50 + 2 * c;
        const half2v v = __builtin_amdgcn_cvt_pkrtz(Wp[base], Wp[base + 1]);
        val = __builtin_bit_cast(unsigned int, v);
      }
      pw[idx] = val;
    }
    return;
  }

  if (tid < NW) idxs[tid] = doc[s * NW + tid];
  __syncthreads();

  // Phase B: column sums of the 64 gathered rows, 2 groups x 32-deep.
  const int p = tid >> 8, et = tid & 255;
  for (int e = et; e < NE; e += 256) {
    float acc = 0.f;
    const int w0 = p * 32;
#pragma unroll 16
    for (int w = w0; w < w0 + 32; ++w)
      acc += emb[(size_t)idxs[w] * NE + e];
    if (p == 0) sv[0][e] = acc; else ph1[e] = acc;
    if (p == 0) {
      sv[1][e] = emb[(size_t)idxs[0]  * NE + e];
      sv[2][e] = emb[(size_t)idxs[1]  * NE + e];
    } else {
      sv[3][e] = emb[(size_t)idxs[62] * NE + e];
      sv[4][e] = emb[(size_t)idxs[63] * NE + e];
    }
  }
  __syncthreads();
  if (tid < NE) sv[0][tid] += ph1[tid];
  __syncthreads();

  // Phase C: 5 families x 50 outputs, 300-dots against W_word rows.
  if (tid < 5 * NH) {
    const int fam = tid / NH, i = tid % NH;
    const float4* v4 = (const float4*)&sv[fam][0];
    const float4* w4 = (const float4*)(Wword + (size_t)i * NE);
    float a0 = 0.f, a1 = 0.f;
#pragma unroll
    for (int c = 0; c < NE / 4; ++c) {
      const float4 v = v4[c], w = w4[c];
      a0 += v.x * w.x + v.y * w.y;
      a1 += v.z * w.z + v.w * w.w;
    }
    dots[fam][i] = a0 + a1;
  }
  __syncthreads();

  // Phase D: conv means + tanh + average -> reps_s (octet split + reduce).
  if (tid < 8 * NH) {
    const int o = tid >> 3, part = tid & 7;
    float m1 = 0.f, m2 = 0.f, m3 = 0.f;
    for (int i = part; i < NH; i += 8) {
      const float bw    = bword[i];
      const float total = dots[0][i] + 64.f * bw;
      const float e0  = dots[1][i] + bw;
      const float e1  = dots[2][i] + bw;
      const float e62 = dots[3][i] + bw;
      const float e63 = dots[4][i] + bw;
      m1 += w1[o * NH + i] * total;
      m2 += w2[(o * NH + i) * 2 + 0] * (total - e63)
          + w2[(o * NH + i) * 2 + 1] * (total - e0);
      m3 += w3[(o * NH + i) * 3 + 0] * (total - e62 - e63)
          + w3[(o * NH + i) * 3 + 1] * (total - e0 - e63)
          + w3[(o * NH + i) * 3 + 2] * (total - e0 - e1);
    }
#pragma unroll
    for (int m = 1; m < 8; m <<= 1) {
      m1 += __shfl_xor(m1, m);
      m2 += __shfl_xor(m2, m);
      m3 += __shfl_xor(m3, m);
    }
    if (part == 0) {
      m1 = b1[o] + m1 * (1.f / 64.f);
      m2 = b2[o] + m2 * (1.f / 63.f);
      m3 = b3[o] + m3 * (1.f / 62.f);
      reps_s[o] = (fast_tanh(m1) + fast_tanh(m2) + fast_tanh(m3)) * (1.f / 3.f);
    }
  }
  __syncthreads();

  // Phase E: x-part gate preactivations for both directions.
  if (tid < 6 * NH) {
    const int dg = tid / NH, j = tid % NH;
    const float* Wp; const float* bp;
    switch (dg) {
      case 0: Wp = Wfi; bp = bfi; break;
      case 1: Wp = Wff; bp = bff; break;
      case 2: Wp = Wfg; bp = bfg; break;
      case 3: Wp = Wbi; bp = bbi; break;
      case 4: Wp = Wbf; bp = bbf; break;
      default: Wp = Wbg; bp = bbg; break;
    }
    float acc = bp[j];
    for (int k = 0; k < NH; ++k) acc += Wp[j * 100 + k] * reps_s[k];
    const int dir = dg / 3, gate = dg % 3;
    Xg[((dir * NS + s) * 3 + gate) * NH + j] = acc;
  }
}

// ---------------------------------------------------------------------------
// K2 (exact R12 structure, ONE change): weights read from the contiguous
// [dg][j][28] layout, NO pins -> the compiler's in-loop rematerialized
// loads can merge into global_load_dwordx4 (75 scalar -> ~19 x4).
// 1 block x 2 waves, zero in-loop barriers, depth-4 X prefetch,
// in-block epilogue.
// ---------------------------------------------------------------------------
struct X3 { float i, f, g; };

__global__ __launch_bounds__(128, 1) void k_scan(
    const float* __restrict__ Xg, const unsigned int* __restrict__ pw,
    const float* __restrict__ Wout, const float* __restrict__ bout,
    float* __restrict__ out)
{
  __shared__ float gsum_sh[2 * NH];

  const int tid = threadIdx.x;
  const int d   = tid >> 6;                 // wave = direction
  const int lane = tid & 63;
  const int j   = (lane < NH) ? lane : 0;   // lanes 50..63 shadow lane 0

  // Per-lane contiguous weight rows (112B stride, 16B aligned).
  const unsigned int* wpI = pw + ((d * 3 + 0) * 50 + j) * 28;
  const unsigned int* wpF = pw + ((d * 3 + 1) * 50 + j) * 28;
  const unsigned int* wpG = pw + ((d * 3 + 2) * 50 + j) * 28;

  half2v wi2[25], wf2[25], wg2[25];
#pragma unroll
  for (int c = 0; c < 25; ++c) {
    wi2[c] = __builtin_bit_cast(half2v, wpI[c]);
    wf2[c] = __builtin_bit_cast(half2v, wpF[c]);
    wg2[c] = __builtin_bit_cast(half2v, wpG[c]);
  }

  const float* Xd = Xg + d * NS * 3 * NH;

  auto ldx = [&](int t) -> X3 {
    const int tt = d ? (NS - 1 - t) : t;
    X3 r;
    r.i = Xd[tt * 150 + j];
    r.f = Xd[tt * 150 + 50 + j];
    r.g = Xd[tt * 150 + 100 + j];
    return r;
  };

  float hj = 0.f, hs = 0.f;

  auto dostep = [&](X3 x) {
    float ai0 = x.i, af0 = x.f, ag0 = x.g;
    float ai1 = 0.f, af1 = 0.f, ag1 = 0.f;
    const float hpart = __builtin_bit_cast(float,
        __builtin_amdgcn_ds_swizzle(__builtin_bit_cast(int, hj), 0x041F));
    const half2v hpk = __builtin_amdgcn_cvt_pkrtz(hj, hpart);
    const int packed = __builtin_bit_cast(int, hpk);
#pragma unroll
    for (int c = 0; c < 25; ++c) {
      const half2v hk2 = __builtin_bit_cast(half2v,
          __builtin_amdgcn_readlane(packed, 2 * c));
      if (c & 1) {
        ai1 = fdot2(wi2[c], hk2, ai1);
        af1 = fdot2(wf2[c], hk2, af1);
        ag1 = fdot2(wg2[c], hk2, ag1);
      } else {
        ai0 = fdot2(wi2[c], hk2, ai0);
        af0 = fdot2(wf2[c], hk2, af0);
        ag0 = fdot2(wg2[c], hk2, ag0);
      }
    }
    const float it = fast_sigmoid(ai0 + ai1);
    const float ft = fast_sigmoid(af0 + af1);
    const float gt = fast_tanh(ag0 + ag1);
    hj = fast_tanh(it * gt + ft * hj);
    hs += hj;
  };

  // Depth-4 rolling prefetch: named slots, statically indexed.
  X3 p0 = ldx(0), p1 = ldx(1), p2 = ldx(2), p3 = ldx(3);

#pragma unroll 1
  for (int k = 0; k < NS / 4; ++k) {
    const int n = 4 * k;
    const int q0 = (n + 4 < NS) ? n + 4 : NS - 1;
    const int q1 = (n + 5 < NS) ? n + 5 : NS - 1;
    const int q2 = (n + 6 < NS) ? n + 6 : NS - 1;
    const int q3 = (n + 7 < NS) ? n + 7 : NS - 1;
    X3 c0 = p0; p0 = ldx(q0); dostep(c0);
    X3 c1 = p1; p1 = ldx(q1); dostep(c1);
    X3 c2 = p2; p2 = ldx(q2); dostep(c2);
    X3 c3 = p3; p3 = ldx(q3); dostep(c3);
  }

  if (lane < NH) gsum_sh[d * NH + lane] = hs * (1.f / 64.f);
  __syncthreads();

  // Epilogue (wave 0): logits + softmax
  if (d == 0) {
    float lg = 0.f;
    if (lane < NO) {
      float acc = bout[lane];
      for (int k = 0; k < 2 * NH; ++k) acc += Wout[lane * 2 * NH + k] * gsum_sh[k];
      lg = acc;
    }
    const float l0 = __shfl(lg, 0), l1 = __shfl(lg, 1), l2 = __shfl(lg, 2),
                l3 = __shfl(lg, 3), l4 = __shfl(lg, 4);
    if (lane == 0) {
      const float m = fmaxf(fmaxf(fmaxf(l0, l1), fmaxf(l2, l3)), l4);
      const float e0 = __expf(l0 - m), e1 = __expf(l1 - m), e2 = __expf(l2 - m),
                  e3 = __expf(l3 - m), e4 = __expf(l4 - m);
      const float se = e0 + e1 + e2 + e3 + e4;
      out[0] = e0 / se; out[1] = e1 / se; out[2] = e2 / se;
      out[3] = e3 / se; out[4] = e4 / se;
    }
  }
}

extern "C" void kernel_launch(void* const* d_in, const int* in_sizes, int n_in,
                              void* d_out, int out_size, void* d_ws, size_t ws_size,
                              hipStream_t stream) {
  const int*   doc   = (const int*)  d_in[0];
  const float* emb   = (const float*)d_in[1];
  const float* Wword = (const float*)d_in[2];
  const float* bword = (const float*)d_in[3];
  const float* w1    = (const float*)d_in[4];
  const float* b1    = (const float*)d_in[5];
  const float* w2    = (const float*)d_in[6];
  const float* b2    = (const float*)d_in[7];
  const float* w3    = (const float*)d_in[8];
  const float* b3    = (const float*)d_in[9];
  const float* Wfi   = (const float*)d_in[10];
  const float* bfi   = (const float*)d_in[11];
  const float* Wff   = (const float*)d_in[12];
  const float* bff   = (const float*)d_in[13];
  const float* Wfg   = (const float*)d_in[14];
  const float* bfg   = (const float*)d_in[15];
  const float* Wbi   = (const float*)d_in[16];
  const float* bbi   = (const float*)d_in[17];
  const float* Wbf   = (const float*)d_in[18];
  const float* bbf   = (const float*)d_in[19];
  const float* Wbg   = (const float*)d_in[20];
  const float* bbg   = (const float*)d_in[21];
  const float* Wout  = (const float*)d_in[22];
  const float* bout  = (const float*)d_in[23];

  float* Xg = (float*)d_ws + 64;                                  // 19200 floats
  unsigned int* pw = (unsigned int*)((float*)d_ws + 64 + 19200);  // 8400 u32

  k_reps<<<dim3(NS + 1), dim3(512), 0, stream>>>(
      doc, emb, Wword, bword, w1, b1, w2, b2, w3, b3,
      Wfi, bfi, Wff, bff, Wfg, bfg, Wbi, bbi, Wbf, bbf, Wbg, bbg,
      Xg, pw);

  k_scan<<<dim3(1), dim3(128), 0, stream>>>(
      Xg, pw, Wout, bout, (float*)d_out);
}